// Round 1
// baseline (822.212 us; speedup 1.0000x reference)
//
#include <hip/hip_runtime.h>

#define NHEAD 256
#define NST   64
#define LSEQ  4096
#define NCHK  64   // LSEQ / 64 chunks of 64 steps

// ws layout (floats):
//  Ab : [256][64][64] @ 0
//  Bb : [256][64]     @ 1048576
//  Kk : [256][64][64] @ 1064960   (K[d][n] = (Ab^d Bb)[n])
//  S  : [256][64][64] @ 2113536   (chunk-start states)

// ---------------- K1: per-head bilinear discretization -----------------
// M = I - dt/2*A is LOWER-TRIANGULAR (HiPPO A is lower-tri), diag >= 1.
// Forward-substitute 65 RHS columns [I + dt/2*A | dt*B] -> [Ab | Bb].
__global__ __launch_bounds__(256) void k1_solve(
    const float* __restrict__ A, const float* __restrict__ Bv,
    const float* __restrict__ dtv, float* __restrict__ Ab,
    float* __restrict__ Bb) {
  const int h = blockIdx.x;
  const int t = threadIdx.x;
  __shared__ float M[64][64];
  __shared__ float X[64][66];
  __shared__ float invd[64];
  const float dt = dtv[h];
  const float* Ah = A + h * 4096;
  for (int idx = t; idx < 4096; idx += 256) {
    const int r = idx >> 6, c = idx & 63;
    const float a = Ah[idx];
    const float half = 0.5f * dt * a;
    const float id = (r == c) ? 1.0f : 0.0f;
    M[r][c] = id - half;
    X[r][c] = id + half;
  }
  if (t < 64) {
    X[t][64] = dt * Bv[h * 64 + t];
    invd[t] = 1.0f / (1.0f - 0.5f * dt * Ah[t * 64 + t]);
  }
  __syncthreads();
  for (int k = 0; k < 64; ++k) {
    if (t < 65) X[k][t] *= invd[k];
    __syncthreads();
    const int nwork = (63 - k) * 65;
    for (int idx = t; idx < nwork; idx += 256) {
      const int r = k + 1 + idx / 65;
      const int c = idx % 65;
      X[r][c] -= M[r][k] * X[k][c];
    }
    __syncthreads();
  }
  for (int idx = t; idx < 4096; idx += 256)
    Ab[h * 4096 + idx] = X[idx >> 6][idx & 63];
  if (t < 64) Bb[h * 64 + t] = X[t][64];
}

// ---------------- K2: per-head kernel chain, Ab^64, chunk states --------
__global__ __launch_bounds__(256) void k2_perhead(
    const float* __restrict__ u, const float* __restrict__ Ab,
    const float* __restrict__ Bb, float* __restrict__ Kk,
    float* __restrict__ S) {
  const int h = blockIdx.x;
  const int t = threadIdx.x;
  __shared__ float AT[64][65];   // transpose of current matrix (padded)
  __shared__ float cur[64][64];  // current matrix: Ab -> ... -> Ab^64
  __shared__ float Kl[64][64];   // K[d][n]; reused as matmul tmp
  __shared__ float ul[64][65];   // ul[c][j] = u[c*64+j] (padded)
  __shared__ float Zl[64][64];   // Z[c][n]
  __shared__ float red[4][64];
  __shared__ float sv[64];

  const float* Abh = Ab + h * 4096;
  for (int idx = t; idx < 4096; idx += 256) {
    const float v = Abh[idx];
    const int r = idx >> 6, c = idx & 63;
    cur[r][c] = v;
    AT[c][r] = v;
  }
  for (int idx = t; idx < 4096; idx += 256) ul[idx >> 6][idx & 63] = u[idx];
  if (t < 64) Kl[0][t] = Bb[h * 64 + t];
  __syncthreads();

  // kernel chain: K[d] = Ab * K[d-1]
  {
    const int n = t & 63, q = t >> 6;
    for (int d = 1; d < 64; ++d) {
      float p = 0.f;
#pragma unroll
      for (int j = 0; j < 16; ++j) p += AT[q * 16 + j][n] * Kl[d - 1][q * 16 + j];
      red[q][n] = p;
      __syncthreads();
      if (t < 64) Kl[d][t] = red[0][t] + red[1][t] + red[2][t] + red[3][t];
      __syncthreads();
    }
  }
  for (int idx = t; idx < 4096; idx += 256)
    Kk[h * 4096 + idx] = Kl[idx >> 6][idx & 63];

  // Z[c][n] = sum_j u[c*64+j] * K[63-j][n]
  {
    const int c = t >> 2, g = t & 3;
    float acc[16];
#pragma unroll
    for (int m = 0; m < 16; ++m) acc[m] = 0.f;
    for (int j = 0; j < 64; ++j) {
      const float uu = ul[c][j];
#pragma unroll
      for (int q4 = 0; q4 < 4; ++q4) {
        const float4 kv =
            *reinterpret_cast<const float4*>(&Kl[63 - j][g * 16 + q4 * 4]);
        acc[q4 * 4 + 0] += uu * kv.x;
        acc[q4 * 4 + 1] += uu * kv.y;
        acc[q4 * 4 + 2] += uu * kv.z;
        acc[q4 * 4 + 3] += uu * kv.w;
      }
    }
#pragma unroll
    for (int m = 0; m < 16; ++m) Zl[c][g * 16 + m] = acc[m];
  }
  __syncthreads();

  // 6 squarings: cur <- cur*cur  => Ab^64 (AT kept in sync as transpose)
  for (int sq = 0; sq < 6; ++sq) {
    const int nb = t >> 4, mb = t & 15;  // 4x4 output block per thread
    float acc2[16];
#pragma unroll
    for (int m = 0; m < 16; ++m) acc2[m] = 0.f;
#pragma unroll 4
    for (int k = 0; k < 64; ++k) {
      const float4 bv = *reinterpret_cast<const float4*>(&cur[k][mb * 4]);
#pragma unroll
      for (int r = 0; r < 4; ++r) {
        const float a = AT[k][nb * 4 + r];
        acc2[r * 4 + 0] += a * bv.x;
        acc2[r * 4 + 1] += a * bv.y;
        acc2[r * 4 + 2] += a * bv.z;
        acc2[r * 4 + 3] += a * bv.w;
      }
    }
#pragma unroll
    for (int r = 0; r < 4; ++r)
      *reinterpret_cast<float4*>(&Kl[nb * 4 + r][mb * 4]) =
          make_float4(acc2[r * 4 + 0], acc2[r * 4 + 1], acc2[r * 4 + 2],
                      acc2[r * 4 + 3]);
    __syncthreads();
    for (int idx = t; idx < 4096; idx += 256) {
      const int r = idx >> 6, c = idx & 63;
      const float v = Kl[r][c];
      cur[r][c] = v;
      AT[c][r] = v;
    }
    __syncthreads();
  }

  // chunk-state recursion: S[h][c] = s_c ; s_{c+1} = Ab^64 s_c + Z_c
  {
    const int n = t & 63, q = t >> 6;
    if (t < 64) sv[t] = 0.f;
    __syncthreads();
    for (int c = 0; c < NCHK; ++c) {
      if (t < 64) S[(h * 64 + c) * 64 + t] = sv[t];
      float p = 0.f;
#pragma unroll
      for (int j = 0; j < 16; ++j) p += AT[q * 16 + j][n] * sv[q * 16 + j];
      red[q][n] = p;
      __syncthreads();
      if (t < 64)
        sv[t] = red[0][t] + red[1][t] + red[2][t] + red[3][t] + Zl[c][t];
      __syncthreads();
    }
  }
}

// ---------------- K3: per-(head,chunk) output tile ----------------------
// out[c*64+i][h][n] = sum_{d<=i} u[c*64+i-d]*K[d][n] + (Ab^{i+1} s_c)[n]
__global__ __launch_bounds__(256) void k3_out(
    const float* __restrict__ u, const float* __restrict__ Ab,
    const float* __restrict__ Kk, const float* __restrict__ S,
    float* __restrict__ out) {
  const int c = blockIdx.x;
  const int h = blockIdx.y;
  const int t = threadIdx.x;
  __shared__ float Ksh[64][64];
  __shared__ float AT[64][65];
  __shared__ float ob[64][64];
  __shared__ float uc[64];
  __shared__ float w[64];
  __shared__ float red[4][64];

  for (int idx = t; idx < 4096; idx += 256)
    Ksh[idx >> 6][idx & 63] = Kk[h * 4096 + idx];
  for (int idx = t; idx < 4096; idx += 256) {
    const int r = idx >> 6, cc = idx & 63;
    AT[cc][r] = Ab[h * 4096 + idx];
  }
  if (t < 64) uc[t] = u[c * 64 + t];
  if (t < 64) w[t] = S[(h * 64 + c) * 64 + t];
  __syncthreads();

  // main (triangular Toeplitz conv)
  {
    const int i = t >> 2, g = t & 3;
    float acc[16];
#pragma unroll
    for (int m = 0; m < 16; ++m) acc[m] = 0.f;
    for (int d = 0; d <= i; ++d) {
      const float uu = uc[i - d];
#pragma unroll
      for (int q4 = 0; q4 < 4; ++q4) {
        const float4 kv =
            *reinterpret_cast<const float4*>(&Ksh[d][g * 16 + q4 * 4]);
        acc[q4 * 4 + 0] += uu * kv.x;
        acc[q4 * 4 + 1] += uu * kv.y;
        acc[q4 * 4 + 2] += uu * kv.z;
        acc[q4 * 4 + 3] += uu * kv.w;
      }
    }
#pragma unroll
    for (int q4 = 0; q4 < 4; ++q4)
      *reinterpret_cast<float4*>(&ob[i][g * 16 + q4 * 4]) =
          make_float4(acc[q4 * 4 + 0], acc[q4 * 4 + 1], acc[q4 * 4 + 2],
                      acc[q4 * 4 + 3]);
  }
  __syncthreads();

  // correction chain: w <- Ab*w ; ob[i][:] += w
  {
    const int n = t & 63, q = t >> 6;
    for (int i = 0; i < 64; ++i) {
      float p = 0.f;
#pragma unroll
      for (int j = 0; j < 16; ++j) p += AT[q * 16 + j][n] * w[q * 16 + j];
      red[q][n] = p;
      __syncthreads();
      if (t < 64) {
        const float wn = red[0][t] + red[1][t] + red[2][t] + red[3][t];
        w[t] = wn;
        ob[i][t] += wn;
      }
      __syncthreads();
    }
  }

  // store tile (rows l = c*64 + r, 256B contiguous per row)
  for (int idx = t; idx < 1024; idx += 256) {
    const int r = idx >> 4, q4 = idx & 15;
    const int l = c * 64 + r;
    *reinterpret_cast<float4*>(&out[(l * NHEAD + h) * 64 + q4 * 4]) =
        *reinterpret_cast<const float4*>(&ob[r][q4 * 4]);
  }
}

extern "C" void kernel_launch(void* const* d_in, const int* in_sizes, int n_in,
                              void* d_out, int out_size, void* d_ws,
                              size_t ws_size, hipStream_t stream) {
  const float* u = (const float*)d_in[0];
  const float* A = (const float*)d_in[1];
  const float* B = (const float*)d_in[2];
  const float* dt = (const float*)d_in[3];
  float* ws = (float*)d_ws;
  float* Ab = ws;                 // 1048576
  float* Bb = ws + 1048576;       // 16384
  float* Kk = ws + 1064960;       // 1048576
  float* S = ws + 2113536;        // 1048576
  float* out = (float*)d_out;

  k1_solve<<<dim3(NHEAD), dim3(256), 0, stream>>>(A, B, dt, Ab, Bb);
  k2_perhead<<<dim3(NHEAD), dim3(256), 0, stream>>>(u, Ab, Bb, Kk, S);
  k3_out<<<dim3(NCHK, NHEAD), dim3(256), 0, stream>>>(u, Ab, Kk, S, out);
}

// Round 2
// 130.503 us; speedup vs baseline: 6.3003x; 6.3003x over previous
//
#include <hip/hip_runtime.h>

#define NHEAD 256

typedef _Float16 f16x8 __attribute__((ext_vector_type(8)));
typedef float f32x4 __attribute__((ext_vector_type(4)));

// ---- swizzled [64][64] f16 matrix helpers (16B-unit XOR swizzle: unit ^= row&7)
__device__ __forceinline__ int mel(int r, int c) {
  return (r << 6) + ((((c >> 3) ^ r) & 7) << 3) + (c & 7);
}
__device__ __forceinline__ f16x8 ldfrag(const _Float16* M, int r, int u) {
  return *(const f16x8*)(M + (r << 6) + (((u ^ r) & 7) << 3));
}
__device__ __forceinline__ f32x4 MF(f16x8 a, f16x8 b, f32x4 c) {
  return __builtin_amdgcn_mfma_f32_16x16x32_f16(a, b, c, 0, 0, 0);
}

// prep matmul: D = A(rows ar0..) * B, B given via BT = B^T row-major ([col][k]).
// 4 waves, wave w = colblock. Writes D row-major AND transposed copy.
__device__ __forceinline__ void mmstep(const _Float16* A, int ar0, const _Float16* BT,
                                       _Float16* Dr, _Float16* Dt, int dr0, int nrb,
                                       int w, int c15, int g) {
  f16x8 b0 = ldfrag(BT, (w << 4) + c15, g);
  f16x8 b1 = ldfrag(BT, (w << 4) + c15, 4 + g);
  for (int ib = 0; ib < nrb; ++ib) {
    f32x4 acc = {0.f, 0.f, 0.f, 0.f};
    f16x8 a0 = ldfrag(A, ar0 + (ib << 4) + c15, g);
    f16x8 a1 = ldfrag(A, ar0 + (ib << 4) + c15, 4 + g);
    acc = MF(a0, b0, acc);
    acc = MF(a1, b1, acc);
#pragma unroll
    for (int j = 0; j < 4; ++j) {
      int rr = dr0 + (ib << 4) + (g << 2) + j;
      int cc = (w << 4) + c15;
      _Float16 v = (_Float16)acc[j];
      Dr[mel(rr, cc)] = v;
      Dt[mel(cc, rr)] = v;
    }
  }
}

// ---------------- K1: per-head bilinear discretization (f32, unchanged) ----
__global__ __launch_bounds__(256) void k1_solve(
    const float* __restrict__ A, const float* __restrict__ Bv,
    const float* __restrict__ dtv, float* __restrict__ Ab,
    float* __restrict__ Bb) {
  const int h = blockIdx.x;
  const int t = threadIdx.x;
  __shared__ float M[64][64];
  __shared__ float X[64][66];
  __shared__ float invd[64];
  const float dt = dtv[h];
  const float* Ah = A + h * 4096;
  for (int idx = t; idx < 4096; idx += 256) {
    const int r = idx >> 6, c = idx & 63;
    const float a = Ah[idx];
    const float half = 0.5f * dt * a;
    const float id = (r == c) ? 1.0f : 0.0f;
    M[r][c] = id - half;
    X[r][c] = id + half;
  }
  if (t < 64) {
    X[t][64] = dt * Bv[h * 64 + t];
    invd[t] = 1.0f / (1.0f - 0.5f * dt * Ah[t * 64 + t]);
  }
  __syncthreads();
  for (int k = 0; k < 64; ++k) {
    if (t < 65) X[k][t] *= invd[k];
    __syncthreads();
    const int nwork = (63 - k) * 65;
    for (int idx = t; idx < nwork; idx += 256) {
      const int r = k + 1 + idx / 65;
      const int c = idx % 65;
      X[r][c] -= M[r][k] * X[k][c];
    }
    __syncthreads();
  }
  for (int idx = t; idx < 4096; idx += 256)
    Ab[h * 4096 + idx] = X[idx >> 6][idx & 63];
  if (t < 64) Bb[h * 64 + t] = X[t][64];
}

// ---------------- K2: fused per-head lag-256 chunked scan via MFMA ----------
// x_l = sum_{t<4} sum_{d<64} u[l-64t-d]*(G^t K[d]) + G^4 x_{l-256}
// 4 waves = 4 independent chains (c = w + 4m), 16 stages each, no barriers
// in the main loop. B-operands (BK_t stack + (G^4)^T) persist in VGPRs.
__global__ __launch_bounds__(256, 1) void k2_fused(
    const float* __restrict__ u, const float* __restrict__ Abg,
    const float* __restrict__ Bbg, float* __restrict__ out) {
  const int h = blockIdx.x;
  const int t = threadIdx.x;
  const int w = t >> 6;          // wave / chain id
  const int lane = t & 63;
  const int c15 = lane & 15;
  const int g = lane >> 4;

  __shared__ __align__(16) _Float16 URV[4 * 4616];  // 4 shift-staggered reversed u copies
  __shared__ __align__(16) _Float16 RING[4 * 4096]; // per-chain X state (f16)
  __shared__ __align__(16) _Float16 PBs[6 * 4096];  // prep buffers
  __shared__ float RED[4][64];
  __shared__ float KC[64];

  _Float16* PB0 = PBs;
  _Float16* PB1 = PBs + 4096;
  _Float16* PB2 = PBs + 2 * 4096;  // Kmat (rows d = K[d])
  _Float16* PB3 = PBs + 3 * 4096;  // KmatT
  _Float16* PB4 = PBs + 4 * 4096;
  _Float16* PB5 = PBs + 5 * 4096;

  // --- stage: reversed/padded u copies; Ab f16 (row + trans); Kmat row 0 ---
  for (int s = 0; s < 4; ++s)
    for (int x = t; x < 4616; x += 256) {
      int q = 4095 - x - s;                     // URV[s][x] = u[4095-(x+s)], 0 pad
      URV[s * 4616 + x] = (q >= 0) ? (_Float16)u[q] : (_Float16)0.f;
    }
  for (int idx = t; idx < 4096; idx += 256) {
    int r = idx >> 6, cc = idx & 63;
    _Float16 v = (_Float16)Abg[(size_t)h * 4096 + idx];
    PB0[mel(r, cc)] = v;   // Ab row-major
    PB1[mel(cc, r)] = v;   // Ab^T
  }
  if (t < 64) {
    float bb = Bbg[h * 64 + t];
    KC[t] = bb;
    PB2[mel(0, t)] = (_Float16)bb;
    PB3[mel(t, 0)] = (_Float16)bb;
  }
  __syncthreads();

  // --- Kmat rows 1..15: f32 matvec chain K[d] = Ab K[d-1] ---
  {
    const int mrow = t & 63, q = t >> 6;
    for (int d = 1; d < 16; ++d) {
      const float4* ar = (const float4*)(Abg + (size_t)h * 4096 + mrow * 64 + q * 16);
      float p = 0.f;
#pragma unroll
      for (int j4 = 0; j4 < 4; ++j4) {
        float4 av = ar[j4];
        const int jb = q * 16 + j4 * 4;
        p += av.x * KC[jb] + av.y * KC[jb + 1] + av.z * KC[jb + 2] + av.w * KC[jb + 3];
      }
      RED[q][mrow] = p;
      __syncthreads();
      if (t < 64) {
        float s2 = RED[0][t] + RED[1][t] + RED[2][t] + RED[3][t];
        KC[t] = s2;
        PB2[mel(d, t)] = (_Float16)s2;
        PB3[mel(t, d)] = (_Float16)s2;
      }
      __syncthreads();
    }
  }

  // --- power ladder + Kmat expansion ---
  mmstep(PB0, 0, PB1, PB4, PB5, 0, 4, w, c15, g); __syncthreads();   // Ab^2
  mmstep(PB4, 0, PB5, PB0, PB1, 0, 4, w, c15, g); __syncthreads();   // Ab^4
  mmstep(PB0, 0, PB1, PB4, PB5, 0, 4, w, c15, g); __syncthreads();   // Ab^8
  mmstep(PB4, 0, PB5, PB0, PB1, 0, 4, w, c15, g); __syncthreads();   // Ab^16 -> PB0/1
  mmstep(PB0, 0, PB1, PB4, PB5, 0, 4, w, c15, g); __syncthreads();   // Ab^32 -> PB4/5
  mmstep(PB2, 0, PB0, PB2, PB3, 16, 1, w, c15, g); __syncthreads();  // K[16..31] = Kmat(0..15)@Ab16^T
  mmstep(PB2, 0, PB4, PB2, PB3, 32, 2, w, c15, g); __syncthreads();  // K[32..63] = Kmat(0..31)@Ab32^T
  mmstep(PB4, 0, PB5, PB0, PB1, 0, 4, w, c15, g); __syncthreads();   // Ab^64: G->PB0, G^T->PB1

  f16x8 bt[8][4];  // conv B-frags: [2*t + kstep][colblock]
  f16x8 bc[2][4];  // correction B-frags (G^4)^T
  auto LB = [&](f16x8* dst, const _Float16* BT, int kk) {
#pragma unroll
    for (int nb = 0; nb < 4; ++nb) dst[nb] = ldfrag(BT, (nb << 4) + c15, (kk << 2) + g);
  };

  LB(bt[0], PB3, 0); LB(bt[1], PB3, 1);                              // BKT_0 = Kmat^T
  mmstep(PB2, 0, PB0, PB4, PB5, 0, 4, w, c15, g); __syncthreads();   // BK1 = Kmat@G^T
  LB(bt[2], PB5, 0); LB(bt[3], PB5, 1);
  mmstep(PB4, 0, PB0, PB2, PB3, 0, 4, w, c15, g); __syncthreads();   // BK2
  LB(bt[4], PB3, 0); LB(bt[5], PB3, 1);
  mmstep(PB2, 0, PB0, PB4, PB5, 0, 4, w, c15, g); __syncthreads();   // BK3
  LB(bt[6], PB5, 0); LB(bt[7], PB5, 1);
  mmstep(PB1, 0, PB0, PB2, PB3, 0, 4, w, c15, g); __syncthreads();   // gT2 = G^T@G^T
  mmstep(PB2, 0, PB3, PB4, PB1, 0, 4, w, c15, g); __syncthreads();   // gT4; trans(G^4 row) -> PB1
  LB(bc[0], PB1, 0); LB(bc[1], PB1, 1);
  __syncthreads();

  // --- chains: 16 stages, barrier-free ---
  _Float16* ringw = RING + (w << 12);
  float* outh = out + (h << 6);
  const int lanebase = (g << 3) - c15;  // per-lane URV offset piece

#pragma unroll 1
  for (int mstep = 0; mstep < 16; ++mstep) {
    const int c = w + (mstep << 2);
    f32x4 acc[4][4];
#pragma unroll
    for (int ib = 0; ib < 4; ++ib)
#pragma unroll
      for (int nb = 0; nb < 4; ++nb) acc[ib][nb] = f32x4{0.f, 0.f, 0.f, 0.f};

    // conv: t = 0..3, K-dim 256 total (Toeplitz A from shifted reversed-u copies)
#pragma unroll
    for (int ks = 0; ks < 8; ++ks) {
      const int tt = ks >> 1;
      const int base = 4095 - 64 * (c - tt) + ((ks & 1) << 5) + lanebase;
#pragma unroll
      for (int ib = 0; ib < 4; ++ib) {
        const int m0 = base - (ib << 4);
        const int lo = m0 & 3;
        const uint2* p = (const uint2*)(URV + lo * 4616 + (m0 - lo));
        union { f16x8 hv; uint2 u2[2]; } ua;
        ua.u2[0] = p[0];
        ua.u2[1] = p[1];
#pragma unroll
        for (int nb = 0; nb < 4; ++nb)
          acc[ib][nb] = MF(ua.hv, bt[ks][nb], acc[ib][nb]);
      }
    }
    // correction: X_{c-4} @ (G^4)^T
    if (mstep > 0) {
#pragma unroll
      for (int kk = 0; kk < 2; ++kk)
#pragma unroll
        for (int ib = 0; ib < 4; ++ib) {
          const int row = (ib << 4) + c15;
          f16x8 a = ldfrag(ringw, row, (kk << 2) + g);
#pragma unroll
          for (int nb = 0; nb < 4; ++nb)
            acc[ib][nb] = MF(a, bc[kk][nb], acc[ib][nb]);
        }
    }
    // write state ring (f16) + global out (f32)
    const int ob = c << 6;
#pragma unroll
    for (int ib = 0; ib < 4; ++ib)
#pragma unroll
      for (int nb = 0; nb < 4; ++nb) {
        const int n = (nb << 4) + c15;
#pragma unroll
        for (int j = 0; j < 4; ++j) {
          const int i = (ib << 4) + (g << 2) + j;
          const float v = acc[ib][nb][j];
          ringw[mel(i, n)] = (_Float16)v;
          outh[(size_t)(ob + i) * 16384 + n] = v;
        }
      }
  }
}

extern "C" void kernel_launch(void* const* d_in, const int* in_sizes, int n_in,
                              void* d_out, int out_size, void* d_ws,
                              size_t ws_size, hipStream_t stream) {
  const float* u = (const float*)d_in[0];
  const float* A = (const float*)d_in[1];
  const float* B = (const float*)d_in[2];
  const float* dt = (const float*)d_in[3];
  float* ws = (float*)d_ws;
  float* Ab = ws;            // 1048576 f32
  float* Bb = ws + 1048576;  // 16384 f32
  float* out = (float*)d_out;

  k1_solve<<<dim3(NHEAD), dim3(256), 0, stream>>>(A, B, dt, Ab, Bb);
  k2_fused<<<dim3(NHEAD), dim3(256), 0, stream>>>(u, Ab, Bb, out);
}

// Round 3
// 73.784 us; speedup vs baseline: 11.1435x; 1.7687x over previous
//
#include <hip/hip_runtime.h>

#define NHEAD 256

typedef _Float16 f16x8 __attribute__((ext_vector_type(8)));
typedef float f32x4 __attribute__((ext_vector_type(4)));

// ---- swizzled [64][64] f16 matrix helpers (16B-unit XOR swizzle: unit ^= row&7)
__device__ __forceinline__ int mel(int r, int c) {
  return (r << 6) + ((((c >> 3) ^ r) & 7) << 3) + (c & 7);
}
__device__ __forceinline__ f16x8 ldfrag(const _Float16* M, int r, int u) {
  return *(const f16x8*)(M + (r << 6) + (((u ^ r) & 7) << 3));
}
__device__ __forceinline__ f32x4 MF(f16x8 a, f16x8 b, f32x4 c) {
  return __builtin_amdgcn_mfma_f32_16x16x32_f16(a, b, c, 0, 0, 0);
}

// prep matmul for 8 waves: D = A(rows ar0..) * B, B given via BT = B^T.
// wave w: colblock w&3, rowblocks ib = (w>>2), (w>>2)+2, ...
__device__ __forceinline__ void mmstep8(const _Float16* A, int ar0,
                                        const _Float16* BT, _Float16* Dr,
                                        _Float16* Dt, int dr0, int nrb, int w,
                                        int c15, int g) {
  const int wc = w & 3;
  f16x8 b0 = ldfrag(BT, (wc << 4) + c15, g);
  f16x8 b1 = ldfrag(BT, (wc << 4) + c15, 4 + g);
  for (int ib = (w >> 2); ib < nrb; ib += 2) {
    f32x4 acc = {0.f, 0.f, 0.f, 0.f};
    f16x8 a0 = ldfrag(A, ar0 + (ib << 4) + c15, g);
    f16x8 a1 = ldfrag(A, ar0 + (ib << 4) + c15, 4 + g);
    acc = MF(a0, b0, acc);
    acc = MF(a1, b1, acc);
#pragma unroll
    for (int j = 0; j < 4; ++j) {
      const int rr = dr0 + (ib << 4) + (g << 2) + j;
      const int cc = (wc << 4) + c15;
      const _Float16 v = (_Float16)acc[j];
      Dr[mel(rr, cc)] = v;
      Dt[mel(cc, rr)] = v;
    }
  }
}

// ---------------- fused: solve + prep + lag-256 chunked scan ----------------
// x_l = sum_{t<4} sum_{d<64} u[l-64t-d]*(G^t K[d]) + G^4 x_{l-256},  G = Ab^64
// 8 waves: chain = w&3 (4 independent chains), half = w>>2 owns 32 output rows.
// Main loop: 16 stages/chain, barrier-free (ring rows are wave-private).
__global__ __launch_bounds__(512, 2) void hippo_fused(
    const float* __restrict__ u, const float* __restrict__ Ag,
    const float* __restrict__ Bv, const float* __restrict__ dtv,
    float* __restrict__ out) {
  const int h = blockIdx.x;
  const int t = threadIdx.x;
  const int w = t >> 6;
  const int lane = t & 63;
  const int c15 = lane & 15;
  const int g = lane >> 4;

  __shared__ __align__(16) _Float16 URV[4 * 4616];   // 4 shift-staggered reversed u
  __shared__ __align__(16) _Float16 RING[4 * 4096];  // per-chain X state (f16)
  // UNI: phase1 = f32 solve {M[64][64] | X[64][68] | invd[64]} (34048 B)
  //      phase2 = f16 {PB0|PB1 @0, PB4|PB5 @16384} (49152 B)
  __shared__ __align__(16) char UNI[49152];
  __shared__ __align__(16) _Float16 PB23[2 * 4096];  // PB2|PB3 (never aliased)
  __shared__ float RED[8][68];
  __shared__ float KC[64];

  float* Ms = (float*)UNI;                    // [64][64]
  float* Xs = (float*)(UNI + 16384);          // [64][68]
  float* invd = (float*)(UNI + 16384 + 17408);
  _Float16* PB0 = (_Float16*)UNI;
  _Float16* PB1 = PB0 + 4096;
  _Float16* PB4 = (_Float16*)(UNI + 16384);
  _Float16* PB5 = PB4 + 4096;
  _Float16* PB2 = PB23;
  _Float16* PB3 = PB23 + 4096;

  // --- stage URV + init solve ---
  for (int s = 0; s < 4; ++s)
    for (int x = t; x < 4616; x += 512) {
      const int q = 4095 - x - s;
      URV[s * 4616 + x] = (q >= 0) ? (_Float16)u[q] : (_Float16)0.f;
    }
  const float dt = dtv[h];
  const float* Ah = Ag + (size_t)h * 4096;
  for (int idx = t; idx < 4096; idx += 512) {
    const int r = idx >> 6, c = idx & 63;
    const float a = Ah[idx];
    const float half = 0.5f * dt * a;
    const float id = (r == c) ? 1.0f : 0.0f;
    Ms[r * 64 + c] = id - half;
    Xs[r * 68 + c] = id + half;
  }
  if (t < 64) {
    Xs[t * 68 + 64] = dt * Bv[h * 64 + t];
    Xs[t * 68 + 65] = 0.f;
    Xs[t * 68 + 66] = 0.f;
    Xs[t * 68 + 67] = 0.f;
    invd[t] = 1.0f / (1.0f - 0.5f * dt * Ah[t * 65]);
  }
  __syncthreads();

  // --- 4-pivot blocked forward substitution: X <- M^{-1} X ---
  for (int k = 0; k < 64; k += 4) {
    if (t < 68) {
      const int c = t;
      const float x0 = Xs[k * 68 + c] * invd[k];
      const float x1 = (Xs[(k + 1) * 68 + c] - Ms[(k + 1) * 64 + k] * x0) * invd[k + 1];
      const float x2 = (Xs[(k + 2) * 68 + c] - Ms[(k + 2) * 64 + k] * x0 -
                        Ms[(k + 2) * 64 + k + 1] * x1) * invd[k + 2];
      const float x3 = (Xs[(k + 3) * 68 + c] - Ms[(k + 3) * 64 + k] * x0 -
                        Ms[(k + 3) * 64 + k + 1] * x1 -
                        Ms[(k + 3) * 64 + k + 2] * x2) * invd[k + 3];
      Xs[k * 68 + c] = x0;
      Xs[(k + 1) * 68 + c] = x1;
      Xs[(k + 2) * 68 + c] = x2;
      Xs[(k + 3) * 68 + c] = x3;
    }
    __syncthreads();
    const int nwork = (60 - k) * 17;
    for (int idx = t; idx < nwork; idx += 512) {
      const int r = k + 4 + idx / 17;
      const int cu = (idx % 17) * 4;
      float4 xr = *(float4*)&Xs[r * 68 + cu];
      const float m0 = Ms[r * 64 + k], m1 = Ms[r * 64 + k + 1];
      const float m2 = Ms[r * 64 + k + 2], m3 = Ms[r * 64 + k + 3];
      const float4 a0 = *(float4*)&Xs[k * 68 + cu];
      const float4 a1 = *(float4*)&Xs[(k + 1) * 68 + cu];
      const float4 a2 = *(float4*)&Xs[(k + 2) * 68 + cu];
      const float4 a3 = *(float4*)&Xs[(k + 3) * 68 + cu];
      xr.x -= m0 * a0.x + m1 * a1.x + m2 * a2.x + m3 * a3.x;
      xr.y -= m0 * a0.y + m1 * a1.y + m2 * a2.y + m3 * a3.y;
      xr.z -= m0 * a0.z + m1 * a1.z + m2 * a2.z + m3 * a3.z;
      xr.w -= m0 * a0.w + m1 * a1.w + m2 * a2.w + m3 * a3.w;
      *(float4*)&Xs[r * 68 + cu] = xr;
    }
    __syncthreads();
  }

  // --- Ab f16 (row+trans, overwrites dead M area); Bb -> KC, Kmat row 0 ---
  for (int idx = t; idx < 4096; idx += 512) {
    const int r = idx >> 6, cc = idx & 63;
    const _Float16 v = (_Float16)Xs[r * 68 + cc];
    PB0[mel(r, cc)] = v;
    PB1[mel(cc, r)] = v;
  }
  if (t < 64) {
    const float bb = Xs[t * 68 + 64];
    KC[t] = bb;
    PB2[mel(0, t)] = (_Float16)bb;
    PB3[mel(t, 0)] = (_Float16)bb;
  }
  __syncthreads();

  // --- Kmat rows 1..15: f32 matvec chain K[d] = Ab K[d-1] (Ab = Xs cols 0..63)
  {
    const int mrow = t & 63, q = w;  // 8 groups of 8 columns
    for (int d = 1; d < 16; ++d) {
      const float4* ar = (const float4*)(Xs + mrow * 68 + q * 8);
      const float4 av0 = ar[0], av1 = ar[1];
      const int jb = q * 8;
      RED[q][mrow] = av0.x * KC[jb] + av0.y * KC[jb + 1] + av0.z * KC[jb + 2] +
                     av0.w * KC[jb + 3] + av1.x * KC[jb + 4] + av1.y * KC[jb + 5] +
                     av1.z * KC[jb + 6] + av1.w * KC[jb + 7];
      __syncthreads();
      if (t < 64) {
        float s2 = 0.f;
#pragma unroll
        for (int qq = 0; qq < 8; ++qq) s2 += RED[qq][t];
        KC[t] = s2;
        PB2[mel(d, t)] = (_Float16)s2;
        PB3[mel(t, d)] = (_Float16)s2;
      }
      __syncthreads();
    }
  }

  // --- power ladder + Kmat expansion (PB4/PB5 overwrite dead Xs) ---
  mmstep8(PB0, 0, PB1, PB4, PB5, 0, 4, w, c15, g); __syncthreads();   // Ab^2
  mmstep8(PB4, 0, PB5, PB0, PB1, 0, 4, w, c15, g); __syncthreads();   // Ab^4
  mmstep8(PB0, 0, PB1, PB4, PB5, 0, 4, w, c15, g); __syncthreads();   // Ab^8
  mmstep8(PB4, 0, PB5, PB0, PB1, 0, 4, w, c15, g); __syncthreads();   // Ab^16
  mmstep8(PB0, 0, PB1, PB4, PB5, 0, 4, w, c15, g); __syncthreads();   // Ab^32
  mmstep8(PB2, 0, PB0, PB2, PB3, 16, 1, w, c15, g); __syncthreads();  // K[16..31]
  mmstep8(PB2, 0, PB4, PB2, PB3, 32, 2, w, c15, g); __syncthreads();  // K[32..63]
  mmstep8(PB4, 0, PB5, PB0, PB1, 0, 4, w, c15, g); __syncthreads();   // G=Ab^64 ->PB0, G^T->PB1

  f16x8 bt[8][4];  // conv B-frags: [2*t + khalf][colblock]
  f16x8 bc[2][4];  // correction B-frags (G^4)^T
  auto LB = [&](f16x8* dst, const _Float16* BT, int kk) {
#pragma unroll
    for (int nb = 0; nb < 4; ++nb)
      dst[nb] = ldfrag(BT, (nb << 4) + c15, (kk << 2) + g);
  };

  LB(bt[0], PB3, 0); LB(bt[1], PB3, 1);                               // BK0 = Kmat
  mmstep8(PB2, 0, PB0, PB4, PB5, 0, 4, w, c15, g); __syncthreads();   // BK1 = Kmat@G^T
  LB(bt[2], PB5, 0); LB(bt[3], PB5, 1);
  mmstep8(PB4, 0, PB0, PB2, PB3, 0, 4, w, c15, g); __syncthreads();   // BK2
  LB(bt[4], PB3, 0); LB(bt[5], PB3, 1);
  mmstep8(PB2, 0, PB0, PB4, PB5, 0, 4, w, c15, g); __syncthreads();   // BK3
  LB(bt[6], PB5, 0); LB(bt[7], PB5, 1);
  mmstep8(PB1, 0, PB0, PB2, PB3, 0, 4, w, c15, g); __syncthreads();   // (G^2)^T -> PB2, G^2 -> PB3
  mmstep8(PB2, 0, PB3, PB4, PB1, 0, 4, w, c15, g); __syncthreads();   // (G^4)^T -> PB4, G^4 -> PB1
  LB(bc[0], PB1, 0); LB(bc[1], PB1, 1);
  __syncthreads();

  // --- main loop: 16 stages per chain, 2 waves per chain, barrier-free ---
  const int chain = w & 3;
  const int half = w >> 2;
  _Float16* ringw = RING + (chain << 12);
  float* outh = out + (h << 6);
  const int lanebase = (g << 3) - c15;

#pragma unroll 1
  for (int mstep = 0; mstep < 16; ++mstep) {
    const int c = chain + (mstep << 2);
    f32x4 acc[2][4];
#pragma unroll
    for (int ibl = 0; ibl < 2; ++ibl)
#pragma unroll
      for (int nb = 0; nb < 4; ++nb) acc[ibl][nb] = f32x4{0.f, 0.f, 0.f, 0.f};

    // conv over 4 lag-tiles (K-dim 256), Toeplitz A from shifted reversed-u
#pragma unroll
    for (int ks = 0; ks < 8; ++ks) {
      const int tt = ks >> 1;
      const int base = 4095 - 64 * (c - tt) + ((ks & 1) << 5) + lanebase;
#pragma unroll
      for (int ibl = 0; ibl < 2; ++ibl) {
        const int ib = (half << 1) + ibl;
        const int m0 = base - (ib << 4);
        const int lo = m0 & 3;
        const uint2* p = (const uint2*)(URV + lo * 4616 + (m0 - lo));
        union { f16x8 hv; uint2 u2[2]; } ua;
        ua.u2[0] = p[0];
        ua.u2[1] = p[1];
#pragma unroll
        for (int nb = 0; nb < 4; ++nb)
          acc[ibl][nb] = MF(ua.hv, bt[ks][nb], acc[ibl][nb]);
      }
    }
    // correction: X_{c-4} @ (G^4)^T  (ring rows are this wave's own)
    if (mstep > 0) {
#pragma unroll
      for (int kk = 0; kk < 2; ++kk)
#pragma unroll
        for (int ibl = 0; ibl < 2; ++ibl) {
          const int row = (((half << 1) + ibl) << 4) + c15;
          const f16x8 a = ldfrag(ringw, row, (kk << 2) + g);
#pragma unroll
          for (int nb = 0; nb < 4; ++nb)
            acc[ibl][nb] = MF(a, bc[kk][nb], acc[ibl][nb]);
        }
    }
    // write state ring (f16) + global out (f32)
    const int ob = c << 6;
#pragma unroll
    for (int ibl = 0; ibl < 2; ++ibl)
#pragma unroll
      for (int nb = 0; nb < 4; ++nb) {
        const int n = (nb << 4) + c15;
#pragma unroll
        for (int j = 0; j < 4; ++j) {
          const int i = (((half << 1) + ibl) << 4) + (g << 2) + j;
          const float v = acc[ibl][nb][j];
          ringw[mel(i, n)] = (_Float16)v;
          outh[(size_t)(ob + i) * 16384 + n] = v;
        }
      }
  }
}

extern "C" void kernel_launch(void* const* d_in, const int* in_sizes, int n_in,
                              void* d_out, int out_size, void* d_ws,
                              size_t ws_size, hipStream_t stream) {
  const float* u = (const float*)d_in[0];
  const float* A = (const float*)d_in[1];
  const float* B = (const float*)d_in[2];
  const float* dt = (const float*)d_in[3];
  float* out = (float*)d_out;
  hippo_fused<<<dim3(NHEAD), dim3(512), 0, stream>>>(u, A, B, dt, out);
}